// Round 15
// baseline (208.913 us; speedup 1.0000x reference)
//
#include <hip/hip_runtime.h>
#include <hip/hip_bf16.h>

#define NROWS 8192

typedef __bf16 bf16x8 __attribute__((ext_vector_type(8)));
typedef float f32x4 __attribute__((ext_vector_type(4)));
typedef unsigned short ushort_t;
typedef unsigned int uint_t;

__device__ __forceinline__ ushort_t f2bf(float f) {
  uint_t u = __builtin_bit_cast(uint_t, f);
  u += 0x7fffu + ((u >> 16) & 1u);   // round-to-nearest-even
  return (ushort_t)(u >> 16);
}
__device__ __forceinline__ float bf2f(ushort_t h) {
  uint_t u = ((uint_t)h) << 16;
  return __builtin_bit_cast(float, u);
}
// async global->LDS DMA; LDS dest = uniform base + lane*size
__device__ __forceinline__ void load_lds16(const ushort_t* g, ushort_t* l) {
  __builtin_amdgcn_global_load_lds(
      (const __attribute__((address_space(1))) unsigned int*)g,
      (__attribute__((address_space(3))) unsigned int*)l, 16, 0, 0);
}
__device__ __forceinline__ void load_lds4(const float* g, float* l) {
  __builtin_amdgcn_global_load_lds(
      (const __attribute__((address_space(1))) unsigned int*)g,
      (__attribute__((address_space(3))) unsigned int*)l, 4, 0, 0);
}

// ---------------------------------------------------------------------------
// lin: computes gl = relu(x@W1+b1), h = x@W2+b2 for a 16-row block, then
// emits FRAGMENT-MAJOR packed outputs (R7):
//   glf[jt][kk][lane][8]  : lane=(g,q) holds gl[16jt+q][32kk+8g+e]  (A/B frag)
//   hf [jc][P][t2][lane][8]: lane=(g,q) holds h[64jc+32P+8g+e][16t2+q], with
//                            feature==F -> 1.0 (deg ones-column), >F -> 0
//   sq[r] = sum(bf16(gl[r])^2) fp32
// ---------------------------------------------------------------------------
template<int DIN, int F>
__global__ __launch_bounds__(256) void lin_kernel(
    const float* __restrict__ x,
    const float* __restrict__ W1, const float* __restrict__ b1,
    const float* __restrict__ W2, const float* __restrict__ b2,
    ushort_t* __restrict__ glf, float* __restrict__ sq, ushort_t* __restrict__ hf)
{
  constexpr int ROWS = 16;
  constexpr int RP   = 256 / F;      // row phases handled in parallel
  constexpr int RPT  = ROWS / RP;    // rows per thread
  constexpr int Fp   = F + 16;
  constexpr int NT   = Fp / 16;
  constexpr int KK   = F / 32;
  __shared__ float   xs[ROWS][DIN];
  __shared__ float   hs[ROWS][F];
  __shared__ ushort_t gls[ROWS][F];
  __shared__ float   sqs[ROWS];
  const int t  = threadIdx.x;
  const int m  = blockIdx.x;         // 16-row block index
  const int r0 = m * ROWS;

  for (int i = t; i < ROWS * DIN; i += 256)
    xs[i / DIN][i % DIN] = x[(size_t)(r0 + i / DIN) * DIN + (i % DIN)];
  if (t < ROWS) sqs[t] = 0.f;
  __syncthreads();

  const int c = t % F, rr = t / F;
  float a1[RPT], a2[RPT];
  for (int i = 0; i < RPT; ++i) { a1[i] = b1[c]; a2[i] = b2[c]; }
  for (int k = 0; k < DIN; ++k) {
    float w1 = W1[(size_t)k * F + c];
    float w2 = W2[(size_t)k * F + c];
#pragma unroll
    for (int i = 0; i < RPT; ++i) {
      float xv = xs[rr + i * RP][k];
      a1[i] = fmaf(xv, w1, a1[i]);
      a2[i] = fmaf(xv, w2, a2[i]);
    }
  }
#pragma unroll
  for (int i = 0; i < RPT; ++i) {
    int r = rr + i * RP;
    float g = fmaxf(a1[i], 0.f);
    ushort_t gb = f2bf(g);
    gls[r][c] = gb;
    float gf = bf2f(gb);
    atomicAdd(&sqs[r], gf * gf);
    hs[r][c] = a2[i];
  }
  __syncthreads();
  if (t < ROWS) sq[r0 + t] = sqs[t];

  // ---- glf writer: chunk = (kk, lane); row = lane&15, cols 32kk+8g..+8
  {
    constexpr int CH = KK * 64;
    if (t < CH) {
      int kk = t >> 6, li = t & 63;
      int row = li & 15, c0 = 32 * kk + 8 * (li >> 4);
      uint4 v = *(const uint4*)&gls[row][c0];
      *(uint4*)(glf + ((size_t)(m * KK + kk) * 64 + li) * 8) = v;
    }
  }

  // ---- hf writer: block's 16 n-rows are lanes g∈{glo,glo+1} of frag (jc,P)
  {
    const int jc  = m >> 2;
    const int P   = (m >> 1) & 1;
    const int glo = (m & 1) * 2;
    for (int idx = t; idx < NT * 32; idx += 256) {
      int t2 = idx >> 5, li = idx & 31;
      int gg = li >> 4, q = li & 15;
      int feat = 16 * t2 + q;
      ushort_t tmp[8];
#pragma unroll
      for (int e = 0; e < 8; ++e) {
        if (feat < F)        tmp[e] = f2bf(hs[8 * gg + e][feat]);
        else if (feat == F)  tmp[e] = (ushort_t)0x3F80;  // bf16(1.0)
        else                 tmp[e] = 0;
      }
      int lane = (glo + gg) * 16 + q;
      uint4* dst = (uint4*)(hf + ((size_t)((jc * 2 + P) * NT + t2) * 64 + lane) * 8);
      *dst = *(const uint4*)tmp;
    }
  }
}

// ---------------------------------------------------------------------------
// fused (R15 = R14 + m230 2-phase dbuf): per iter, STAGE(k+1 -> buf^1) is
// issued BEFORE computing buf k (loads fly under phase A/elem/phase B), then
// ONE s_waitcnt vmcnt(0) lgkmcnt(0) + ONE raw s_barrier per iteration.
// R9's failure deviated from this recipe (2 barriers, stage after compute,
// 74KB LDS); R13's ablation showed the un-overlapped stage+drain was ~1/3 of
// runtime. adj stays wave-private (lgkmcnt fences only). LDS 41KB.
// ---------------------------------------------------------------------------
template<int F>
__global__ __launch_bounds__(256) void fused_kernel(
    const ushort_t* __restrict__ glf, const float* __restrict__ sq,
    const ushort_t* __restrict__ hf,
    const float* __restrict__ temp_p, const float* __restrict__ theta_p,
    float* __restrict__ partial)
{
  constexpr int Fp   = F + 16;
  constexpr int NT   = Fp / 16;      // 9 (F=128) or 5 (F=64)
  constexpr int KK   = F / 32;       // 4 or 2
  constexpr int JS   = 8;
  constexpr int JCH  = NROWS / JS;   // 1024 j-rows per block
  constexpr int NIT  = JCH / 32;     // 32 iterations of 32 j's
  constexpr int NCHB = 2 * KK;       // B-frag 1KB chunks per 32-j window
  constexpr int NHF  = NT - 1;       // staged hf chunks (last is const ones)
  constexpr int NCH  = NCHB + NHF;   // 16 (F=128) / 8 (F=64)
  constexpr int SBUF = NCH * 512 + 128;  // ushorts per stage buffer (+sq slot)
  constexpr float EPS = 1.1920929e-07f;
  constexpr float LOG2E = 1.4426950408889634f;
  __shared__ __align__(16) ushort_t stage[2 * SBUF];   // dbuf 33KB / 17KB
  __shared__ __align__(16) ushort_t adjlds[128 * 32];  // 8KB swizzled

  const int w = threadIdx.x >> 6, lane = threadIdx.x & 63;
  const int g = lane >> 4, q = lane & 15;
  const int irow  = blockIdx.x * 128 + 32 * w;  // this wave's private 32 rows
  const int jbase = blockIdx.y * JCH;
  const float c1 = 1.0f + *temp_p;
  const float c0 = 5.0f + *theta_p;
  const float k1 = c1 * LOG2E;        // sigmoid(c0-c1*d) = rcp(1+exp2(k1*d+k0))
  const float k0 = -c0 * LOG2E;

  // hoist A-fragments for both strips and sqi'+EPS
  bf16x8 aF[2][KK];
#pragma unroll
  for (int s = 0; s < 2; ++s)
#pragma unroll
    for (int kk = 0; kk < KK; ++kk)
      aF[s][kk] = *(const bf16x8*)(glf +
          ((size_t)(((irow >> 4) + s) * KK + kk) * 64 + lane) * 8);
  float sqi[2][4];
#pragma unroll
  for (int s = 0; s < 2; ++s)
#pragma unroll
    for (int r = 0; r < 4; ++r) sqi[s][r] = sq[irow + 16 * s + 4 * g + r] + EPS;

  // constant ones-column fragment: h[.][F] = 1.0 -> lanes with q==0
  bf16x8 onesF;
  {
    ushort_t tmp[8];
    ushort_t v = (q == 0) ? (ushort_t)0x3F80 : (ushort_t)0;
#pragma unroll
    for (int e = 0; e < 8; ++e) tmp[e] = v;
    onesF = *(const bf16x8*)tmp;
  }

  // hoisted swizzled adj-write pointers (strip 0); strip 1 = +512 ushorts
  // adj layout: byte = row*64 + ((col*2) ^ (((row>>2)&3)<<4)), 128x32 bf16
  ushort_t* wp[8];
#pragma unroll
  for (int tt = 0; tt < 2; ++tt)
#pragma unroll
    for (int r = 0; r < 4; ++r) {
      int row = 32 * w + 4 * g + r;
      int colb = 32 * tt + 2 * q;
      wp[tt * 4 + r] = (ushort_t*)((char*)adjlds
                        + row * 64 + (colb ^ (((row >> 2) & 3) << 4)));
    }
  // hoisted phase-B adj read pointer (strip 0); strip 1 = +512 ushorts
  const ushort_t* rp;
  {
    int row = 32 * w + q;
    rp = (const ushort_t*)((char*)adjlds
          + row * 64 + ((16 * g) ^ (((row >> 2) & 3) << 4)));
  }

  f32x4 acc[2][NT];
#pragma unroll
  for (int s = 0; s < 2; ++s)
#pragma unroll
    for (int i = 0; i < NT; ++i) acc[s][i] = (f32x4){0.f, 0.f, 0.f, 0.f};

  auto STAGE = [&](int j1, int half) {
    ushort_t* sb = stage + half * SBUF;
    const ushort_t* glB = glf + (size_t)(j1 >> 4) * KK * 512;  // 2 jt x KK
    const ushort_t* glH = hf  + (size_t)(j1 >> 5) * NT * 512;  // this K-half
#pragma unroll
    for (int ch = w; ch < NCH; ch += 4) {
      const ushort_t* src = (ch < NCHB) ? (glB + (size_t)ch * 512)
                                        : (glH + (size_t)(ch - NCHB) * 512);
      load_lds16(src + lane * 8, sb + ch * 512);
    }
    if (w == 3 && lane < 32)
      load_lds4(sq + j1 + lane, (float*)(sb + NCH * 512) + lane);
  };

  // ---- prologue: stage tile 0, drain, barrier
  STAGE(jbase, 0);
  asm volatile("s_waitcnt vmcnt(0)" ::: "memory");
  __builtin_amdgcn_s_barrier();

  int cur = 0;
#pragma unroll 1
  for (int k = 0; k < NIT; ++k) {
    const ushort_t* sb = stage + cur * SBUF;
    // ---- issue next tile's loads FIRST; they fly under this tile's compute
    if (k + 1 < NIT) STAGE(jbase + (k + 1) * 32, cur ^ 1);

    const float* sql = (const float*)(sb + NCH * 512) + q;
    // ---- phase A: S tiles [2x16][32]; each b read feeds BOTH strips
    f32x4 sA[2][2];
    float sqj[2];
#pragma unroll
    for (int tt = 0; tt < 2; ++tt) {
      sqj[tt] = sql[16 * tt];
      f32x4 c0a = (f32x4){0.f, 0.f, 0.f, 0.f};
      f32x4 c1a = (f32x4){0.f, 0.f, 0.f, 0.f};
#pragma unroll
      for (int kk = 0; kk < KK; ++kk) {
        bf16x8 b = *(const bf16x8*)(sb + (tt * KK + kk) * 512 + lane * 8);
        c0a = __builtin_amdgcn_mfma_f32_16x16x32_bf16(aF[0][kk], b, c0a, 0, 0, 0);
        c1a = __builtin_amdgcn_mfma_f32_16x16x32_bf16(aF[1][kk], b, c1a, 0, 0, 0);
      }
      sA[0][tt] = c0a;
      sA[1][tt] = c1a;
    }
    // ---- elementwise, 2 strips x 8: d=max(t1-2s,EPS); adj=rcp(1+exp2(...))
#pragma unroll
    for (int s = 0; s < 2; ++s)
#pragma unroll
      for (int tt = 0; tt < 2; ++tt)
#pragma unroll
        for (int r = 0; r < 4; ++r) {
          float t1 = sqi[s][r] + sqj[tt];
          float d  = fmaxf(fmaf(-2.f, sA[s][tt][r], t1), EPS);
          float e  = __builtin_amdgcn_exp2f(
                       fmaf(k1, __builtin_amdgcn_sqrtf(d), k0));
          float adjv = __builtin_amdgcn_rcpf(1.f + e);
          uint_t u = __builtin_bit_cast(uint_t, adjv) + 0x8000u;  // rnd-half-up
          *(wp[tt * 4 + r] + s * 512) = (ushort_t)(u >> 16);
        }
    // RAW fence (cross-lane, same wave): adj writes visible to reads
    asm volatile("s_waitcnt lgkmcnt(0)" ::: "memory");
    // ---- phase B: acc += adj[32-rows][32] @ h[32][Fp]; hF feeds BOTH strips
    {
      bf16x8 aP0 = *(const bf16x8*)(rp);
      bf16x8 aP1 = *(const bf16x8*)(rp + 512);
#pragma unroll
      for (int t2 = 0; t2 < NT; ++t2) {
        bf16x8 hF = (t2 == NT - 1)
            ? onesF
            : *(const bf16x8*)(sb + (NCHB + t2) * 512 + lane * 8);
        acc[0][t2] = __builtin_amdgcn_mfma_f32_16x16x32_bf16(aP0, hF, acc[0][t2], 0, 0, 0);
        acc[1][t2] = __builtin_amdgcn_mfma_f32_16x16x32_bf16(aP1, hF, acc[1][t2], 0, 0, 0);
      }
    }
    // ---- single per-iter sync: next-tile loads landed; my ds ops retired;
    // all waves done reading buf[cur] before iter k+1 stages into it (dbuf:
    // k+1 writes cur^1; k+2 writes cur -- guarded by THIS barrier chain).
    asm volatile("s_waitcnt vmcnt(0) lgkmcnt(0)" ::: "memory");
    __builtin_amdgcn_s_barrier();
    cur ^= 1;
  }

  // ---- epilogue: wave owns rows irow..irow+31 -> direct disjoint store
  float* op = partial + ((size_t)blockIdx.y * NROWS + irow) * Fp;
#pragma unroll
  for (int s = 0; s < 2; ++s)
#pragma unroll
    for (int t2 = 0; t2 < NT; ++t2)
#pragma unroll
      for (int r = 0; r < 4; ++r)
        op[(size_t)(16 * s + 4 * g + r) * Fp + 16 * t2 + q] = acc[s][t2][r];
}

// x_next = relu(sum_js(partial col c) / sum_js(partial col F))
template<int F, bool RELU>
__global__ __launch_bounds__(256) void reduce_div_kernel(
    const float* __restrict__ partial, float* __restrict__ out)
{
  int idx = blockIdx.x * 256 + threadIdx.x;
  int r = idx / F, c = idx % F;
  size_t base = (size_t)r * (F + 16);
  size_t stride = (size_t)NROWS * (F + 16);
  float s = 0.f, d = 0.f;
#pragma unroll
  for (int js = 0; js < 8; ++js) {
    s += partial[js * stride + base + c];
    d += partial[js * stride + base + F];
  }
  float v = s / d;
  if (RELU) v = fmaxf(v, 0.f);
  out[idx] = v;
}

// out = softmax(sum_js(partial)/deg) rowwise; one wave per row
__global__ __launch_bounds__(64) void reduce_softmax_kernel(
    const float* __restrict__ partial, float* __restrict__ out)
{
  int r = blockIdx.x, c = threadIdx.x;
  size_t base = (size_t)r * 80;
  size_t stride = (size_t)NROWS * 80;
  float v = 0.f, d = 0.f;
#pragma unroll
  for (int js = 0; js < 8; ++js) {
    v += partial[js * stride + base + c];
    d += partial[js * stride + base + 64];
  }
  v /= d;
  float m = v;
  for (int o = 32; o > 0; o >>= 1) m = fmaxf(m, __shfl_xor(m, o, 64));
  float e = __expf(v - m);
  float s = e;
  for (int o = 32; o > 0; o >>= 1) s += __shfl_xor(s, o, 64);
  out[(size_t)r * 64 + c] = e / s;
}

extern "C" void kernel_launch(void* const* d_in, const int* in_sizes, int n_in,
                              void* d_out, int out_size, void* d_ws, size_t ws_size,
                              hipStream_t stream) {
  const float* feat  = (const float*)d_in[0];
  const float* Wgl0  = (const float*)d_in[6];
  const float* bgl0  = (const float*)d_in[7];
  const float* Wgnn0 = (const float*)d_in[8];
  const float* bgnn0 = (const float*)d_in[9];
  const float* Wgl1  = (const float*)d_in[10];
  const float* bgl1  = (const float*)d_in[11];
  const float* Wgnn1 = (const float*)d_in[12];
  const float* bgnn1 = (const float*)d_in[13];
  const float* temp  = (const float*)d_in[14];
  const float* theta = (const float*)d_in[15];
  float* out = (float*)d_out;

  char* ws = (char*)d_ws;
  size_t off = 0;
  auto alloc = [&](size_t bytes) {
    char* p = ws + off;
    off = (off + bytes + 255) & ~(size_t)255;
    return p;
  };
  float*    par0 = (float*)alloc(8ull * NROWS * 144 * 4);  // 37.7 MB
  float*    par1 = par0;  // aliased: par0 is consumed before fused<64> runs
  float*    x1   = (float*)alloc(8192ull * 128 * 4);
  ushort_t* glf0 = (ushort_t*)alloc((8192ull / 16) * 4 * 64 * 8 * 2);  // 2 MB
  ushort_t* glf1 = (ushort_t*)alloc((8192ull / 16) * 2 * 64 * 8 * 2);  // 1 MB
  ushort_t* hf0  = (ushort_t*)alloc((8192ull / 64) * 2 * 9 * 64 * 8 * 2);  // 2.25 MB
  ushort_t* hf1  = (ushort_t*)alloc((8192ull / 64) * 2 * 5 * 64 * 8 * 2);  // 1.25 MB
  float*    sq0  = (float*)alloc(8192ull * 4);
  float*    sq1  = (float*)alloc(8192ull * 4);

  lin_kernel<256, 128><<<512, 256, 0, stream>>>(feat, Wgl0, bgl0, Wgnn0, bgnn0, glf0, sq0, hf0);
  fused_kernel<128><<<dim3(64, 8), 256, 0, stream>>>(glf0, sq0, hf0, temp, theta, par0);
  reduce_div_kernel<128, true><<<(8192 * 128) / 256, 256, 0, stream>>>(par0, x1);

  lin_kernel<128, 64><<<512, 256, 0, stream>>>(x1, Wgl1, bgl1, Wgnn1, bgnn1, glf1, sq1, hf1);
  fused_kernel<64><<<dim3(64, 8), 256, 0, stream>>>(glf1, sq1, hf1, temp, theta, par1);
  reduce_softmax_kernel<<<8192, 64, 0, stream>>>(par1, out);
}

// Round 16
// 150.736 us; speedup vs baseline: 1.3859x; 1.3859x over previous
//
#include <hip/hip_runtime.h>
#include <hip/hip_bf16.h>

#define NROWS 8192

typedef __bf16 bf16x8 __attribute__((ext_vector_type(8)));
typedef float f32x4 __attribute__((ext_vector_type(4)));
typedef unsigned short ushort_t;
typedef unsigned int uint_t;

__device__ __forceinline__ ushort_t f2bf(float f) {
  uint_t u = __builtin_bit_cast(uint_t, f);
  u += 0x7fffu + ((u >> 16) & 1u);   // round-to-nearest-even
  return (ushort_t)(u >> 16);
}
__device__ __forceinline__ float bf2f(ushort_t h) {
  uint_t u = ((uint_t)h) << 16;
  return __builtin_bit_cast(float, u);
}
// async global->LDS DMA; LDS dest = uniform base + lane*size
__device__ __forceinline__ void load_lds16(const ushort_t* g, ushort_t* l) {
  __builtin_amdgcn_global_load_lds(
      (const __attribute__((address_space(1))) unsigned int*)g,
      (__attribute__((address_space(3))) unsigned int*)l, 16, 0, 0);
}
__device__ __forceinline__ void load_lds4(const float* g, float* l) {
  __builtin_amdgcn_global_load_lds(
      (const __attribute__((address_space(1))) unsigned int*)g,
      (__attribute__((address_space(3))) unsigned int*)l, 4, 0, 0);
}

// ---------------------------------------------------------------------------
// prep_w: pack Wcat=[W1|W2] (fp32) into fragment-major bf16 Wf:
//   Wf[((kk*NCT)+ct)*512 + lane*8 + e] = bf16(Wcat[32kk+8g+e][16ct+q])
// One-time per launch; L2-resident, shared by all lin blocks.
// ---------------------------------------------------------------------------
template<int DIN, int F>
__global__ __launch_bounds__(256) void prep_w_kernel(
    const float* __restrict__ W1, const float* __restrict__ W2,
    ushort_t* __restrict__ Wf)
{
  constexpr int NCT = (2 * F) / 16;
  int idx = blockIdx.x * 256 + threadIdx.x;   // grid sized exactly
  int e = idx & 7, lane = (idx >> 3) & 63;
  int ct = (idx >> 9) % NCT, kk = (idx >> 9) / NCT;
  int g = lane >> 4, q = lane & 15;
  int k = 32 * kk + 8 * g + e, c = 16 * ct + q;
  float v = (c < F) ? W1[(size_t)k * F + c] : W2[(size_t)k * F + (c - F)];
  Wf[idx] = f2bf(v);
}

// ---------------------------------------------------------------------------
// lin (R16: MFMA GEMM): per 16-row block computes [gl|h] = x @ [W1|W2] + b
// via bf16 MFMA (A = x rows bf16-rounded from LDS, B = Wf fragment-major,
// bias pre-loaded into accumulator). Results land in the same gls/hs LDS
// tiles; the proven glf/hf/sq packers below are unchanged from R7.
// ---------------------------------------------------------------------------
template<int DIN, int F>
__global__ __launch_bounds__(256) void lin_kernel(
    const float* __restrict__ x, const ushort_t* __restrict__ Wf,
    const float* __restrict__ b1, const float* __restrict__ b2,
    ushort_t* __restrict__ glf, float* __restrict__ sq, ushort_t* __restrict__ hf)
{
  constexpr int Fp   = F + 16;
  constexpr int NT   = Fp / 16;
  constexpr int KK   = F / 32;       // packer fragments (gl)
  constexpr int KKD  = DIN / 32;     // GEMM K-fragments
  constexpr int NCT  = (2 * F) / 16; // output col-tiles (gl|h)
  constexpr int NCTW = NCT / 4;      // col-tiles per wave
  __shared__ float    xs[16][DIN];
  __shared__ float    hs[16][F];
  __shared__ ushort_t gls[16][F];
  __shared__ float    sqs[16];
  const int t  = threadIdx.x;
  const int m  = blockIdx.x;
  const int r0 = m * 16;
  const int w = t >> 6, lane = t & 63, g = lane >> 4, q = lane & 15;

  for (int i = t; i < 16 * DIN; i += 256)
    xs[i / DIN][i % DIN] = x[(size_t)(r0 + i / DIN) * DIN + (i % DIN)];
  if (t < 16) sqs[t] = 0.f;
  __syncthreads();

  // A-frags: lane(g,q) elem e = bf16(xs[q][32kk+8g+e]) — contiguous LDS reads
  bf16x8 aF[KKD];
#pragma unroll
  for (int kk = 0; kk < KKD; ++kk) {
    const float* src = &xs[q][32 * kk + 8 * g];
    __align__(16) ushort_t tmp[8];
#pragma unroll
    for (int e = 0; e < 8; ++e) tmp[e] = f2bf(src[e]);
    aF[kk] = *(const bf16x8*)tmp;
  }
  // acc init = bias broadcast (bias[col] adds to every row)
  f32x4 acc[NCTW];
#pragma unroll
  for (int tl = 0; tl < NCTW; ++tl) {
    int c = 16 * (NCTW * w + tl) + q;
    float bv = (c < F) ? b1[c] : b2[c - F];
    acc[tl] = (f32x4){bv, bv, bv, bv};
  }
  // MFMA K-loop: B-frags contiguous 16B/lane from Wf (L2-shared)
#pragma unroll
  for (int kk = 0; kk < KKD; ++kk)
#pragma unroll
    for (int tl = 0; tl < NCTW; ++tl) {
      bf16x8 bW = *(const bf16x8*)(Wf +
          ((size_t)(kk * NCT) + (NCTW * w + tl)) * 512 + lane * 8);
      acc[tl] = __builtin_amdgcn_mfma_f32_16x16x32_bf16(aF[kk], bW, acc[tl], 0, 0, 0);
    }
  // epilogue: D[row=4g+r][col=16ct+q] -> gls (relu+bf16, +sq) or hs
#pragma unroll
  for (int tl = 0; tl < NCTW; ++tl)
#pragma unroll
    for (int r = 0; r < 4; ++r) {
      int row = 4 * g + r, c = 16 * (NCTW * w + tl) + q;
      float v = acc[tl][r];
      if (c < F) {
        float gv = fmaxf(v, 0.f);
        ushort_t gb = f2bf(gv);
        gls[row][c] = gb;
        float gf = bf2f(gb);
        atomicAdd(&sqs[row], gf * gf);
      } else {
        hs[row][c - F] = v;
      }
    }
  __syncthreads();
  if (t < 16) sq[r0 + t] = sqs[t];

  // ---- glf writer (unchanged): chunk = (kk, lane); row=lane&15
  {
    constexpr int CH = KK * 64;
    if (t < CH) {
      int kk = t >> 6, li = t & 63;
      int row = li & 15, c0 = 32 * kk + 8 * (li >> 4);
      uint4 v = *(const uint4*)&gls[row][c0];
      *(uint4*)(glf + ((size_t)(m * KK + kk) * 64 + li) * 8) = v;
    }
  }
  // ---- hf writer (unchanged): block's 16 n-rows -> frag (jc,P), lanes glo..
  {
    const int jc  = m >> 2;
    const int P   = (m >> 1) & 1;
    const int glo = (m & 1) * 2;
    for (int idx = t; idx < NT * 32; idx += 256) {
      int t2 = idx >> 5, li = idx & 31;
      int gg = li >> 4, qq = li & 15;
      int feat = 16 * t2 + qq;
      ushort_t tmp[8];
#pragma unroll
      for (int e = 0; e < 8; ++e) {
        if (feat < F)        tmp[e] = f2bf(hs[8 * gg + e][feat]);
        else if (feat == F)  tmp[e] = (ushort_t)0x3F80;  // bf16(1.0)
        else                 tmp[e] = 0;
      }
      int ln = (glo + gg) * 16 + qq;
      uint4* dst = (uint4*)(hf + ((size_t)((jc * 2 + P) * NT + t2) * 64 + ln) * 8);
      *dst = *(const uint4*)tmp;
    }
  }
}

// ---------------------------------------------------------------------------
// fused (R14/R15 structure — unchanged this round)
// ---------------------------------------------------------------------------
template<int F>
__global__ __launch_bounds__(256) void fused_kernel(
    const ushort_t* __restrict__ glf, const float* __restrict__ sq,
    const ushort_t* __restrict__ hf,
    const float* __restrict__ temp_p, const float* __restrict__ theta_p,
    float* __restrict__ partial)
{
  constexpr int Fp   = F + 16;
  constexpr int NT   = Fp / 16;
  constexpr int KK   = F / 32;
  constexpr int JS   = 8;
  constexpr int JCH  = NROWS / JS;
  constexpr int NIT  = JCH / 32;
  constexpr int NCHB = 2 * KK;
  constexpr int NHF  = NT - 1;
  constexpr int NCH  = NCHB + NHF;
  constexpr float EPS = 1.1920929e-07f;
  constexpr float LOG2E = 1.4426950408889634f;
  __shared__ __align__(16) ushort_t stage[NCH * 512 + 128];
  __shared__ __align__(16) ushort_t adjlds[128 * 32];

  const int w = threadIdx.x >> 6, lane = threadIdx.x & 63;
  const int g = lane >> 4, q = lane & 15;
  const int irow  = blockIdx.x * 128 + 32 * w;
  const int jbase = blockIdx.y * JCH;
  const float c1 = 1.0f + *temp_p;
  const float c0 = 5.0f + *theta_p;
  const float k1 = c1 * LOG2E;
  const float k0 = -c0 * LOG2E;

  bf16x8 aF[2][KK];
#pragma unroll
  for (int s = 0; s < 2; ++s)
#pragma unroll
    for (int kk = 0; kk < KK; ++kk)
      aF[s][kk] = *(const bf16x8*)(glf +
          ((size_t)(((irow >> 4) + s) * KK + kk) * 64 + lane) * 8);
  float sqi[2][4];
#pragma unroll
  for (int s = 0; s < 2; ++s)
#pragma unroll
    for (int r = 0; r < 4; ++r) sqi[s][r] = sq[irow + 16 * s + 4 * g + r] + EPS;

  bf16x8 onesF;
  {
    __align__(16) ushort_t tmp[8];
    ushort_t v = (q == 0) ? (ushort_t)0x3F80 : (ushort_t)0;
#pragma unroll
    for (int e = 0; e < 8; ++e) tmp[e] = v;
    onesF = *(const bf16x8*)tmp;
  }

  ushort_t* wp[8];
#pragma unroll
  for (int tt = 0; tt < 2; ++tt)
#pragma unroll
    for (int r = 0; r < 4; ++r) {
      int row = 32 * w + 4 * g + r;
      int colb = 32 * tt + 2 * q;
      wp[tt * 4 + r] = (ushort_t*)((char*)adjlds
                        + row * 64 + (colb ^ (((row >> 2) & 3) << 4)));
    }
  const ushort_t* rp;
  {
    int row = 32 * w + q;
    rp = (const ushort_t*)((char*)adjlds
          + row * 64 + ((16 * g) ^ (((row >> 2) & 3) << 4)));
  }
  const float* sql = (const float*)(stage + NCH * 512) + q;

  f32x4 acc[2][NT];
#pragma unroll
  for (int s = 0; s < 2; ++s)
#pragma unroll
    for (int i = 0; i < NT; ++i) acc[s][i] = (f32x4){0.f, 0.f, 0.f, 0.f};

#pragma unroll 1
  for (int k = 0; k < NIT; ++k) {
    const int j0 = jbase + k * 32;
    __syncthreads();
    {
      const ushort_t* glB = glf + (size_t)(j0 >> 4) * KK * 512;
      const ushort_t* glH = hf  + (size_t)(j0 >> 5) * NT * 512;
#pragma unroll
      for (int ch = w; ch < NCH; ch += 4) {
        const ushort_t* src = (ch < NCHB) ? (glB + (size_t)ch * 512)
                                          : (glH + (size_t)(ch - NCHB) * 512);
        load_lds16(src + lane * 8, stage + ch * 512);
      }
      if (w == 3 && lane < 32)
        load_lds4(sq + j0 + lane, (float*)(stage + NCH * 512) + lane);
    }
    __syncthreads();

    f32x4 sA[2][2];
    float sqj[2];
#pragma unroll
    for (int tt = 0; tt < 2; ++tt) {
      sqj[tt] = sql[16 * tt];
      f32x4 c0a = (f32x4){0.f, 0.f, 0.f, 0.f};
      f32x4 c1a = (f32x4){0.f, 0.f, 0.f, 0.f};
#pragma unroll
      for (int kk = 0; kk < KK; ++kk) {
        bf16x8 b = *(const bf16x8*)(stage + (tt * KK + kk) * 512 + lane * 8);
        c0a = __builtin_amdgcn_mfma_f32_16x16x32_bf16(aF[0][kk], b, c0a, 0, 0, 0);
        c1a = __builtin_amdgcn_mfma_f32_16x16x32_bf16(aF[1][kk], b, c1a, 0, 0, 0);
      }
      sA[0][tt] = c0a;
      sA[1][tt] = c1a;
    }
#pragma unroll
    for (int s = 0; s < 2; ++s)
#pragma unroll
      for (int tt = 0; tt < 2; ++tt)
#pragma unroll
        for (int r = 0; r < 4; ++r) {
          float t1 = sqi[s][r] + sqj[tt];
          float d  = fmaxf(fmaf(-2.f, sA[s][tt][r], t1), EPS);
          float e  = __builtin_amdgcn_exp2f(
                       fmaf(k1, __builtin_amdgcn_sqrtf(d), k0));
          float adjv = __builtin_amdgcn_rcpf(1.f + e);
          uint_t u = __builtin_bit_cast(uint_t, adjv) + 0x8000u;
          *(wp[tt * 4 + r] + s * 512) = (ushort_t)(u >> 16);
        }
    asm volatile("s_waitcnt lgkmcnt(0)" ::: "memory");
    {
      bf16x8 aP0 = *(const bf16x8*)(rp);
      bf16x8 aP1 = *(const bf16x8*)(rp + 512);
#pragma unroll
      for (int t2 = 0; t2 < NT; ++t2) {
        bf16x8 hF = (t2 == NT - 1)
            ? onesF
            : *(const bf16x8*)(stage + (NCHB + t2) * 512 + lane * 8);
        acc[0][t2] = __builtin_amdgcn_mfma_f32_16x16x32_bf16(aP0, hF, acc[0][t2], 0, 0, 0);
        acc[1][t2] = __builtin_amdgcn_mfma_f32_16x16x32_bf16(aP1, hF, acc[1][t2], 0, 0, 0);
      }
    }
  }

  float* op = partial + ((size_t)blockIdx.y * NROWS + irow) * Fp;
#pragma unroll
  for (int s = 0; s < 2; ++s)
#pragma unroll
    for (int t2 = 0; t2 < NT; ++t2)
#pragma unroll
      for (int r = 0; r < 4; ++r)
        op[(size_t)(16 * s + 4 * g + r) * Fp + 16 * t2 + q] = acc[s][t2][r];
}

// x_next = relu(sum_js(partial col c) / sum_js(partial col F))
template<int F, bool RELU>
__global__ __launch_bounds__(256) void reduce_div_kernel(
    const float* __restrict__ partial, float* __restrict__ out)
{
  int idx = blockIdx.x * 256 + threadIdx.x;
  int r = idx / F, c = idx % F;
  size_t base = (size_t)r * (F + 16);
  size_t stride = (size_t)NROWS * (F + 16);
  float s = 0.f, d = 0.f;
#pragma unroll
  for (int js = 0; js < 8; ++js) {
    s += partial[js * stride + base + c];
    d += partial[js * stride + base + F];
  }
  float v = s / d;
  if (RELU) v = fmaxf(v, 0.f);
  out[idx] = v;
}

// out = softmax(sum_js(partial)/deg) rowwise; 4 rows/block (wave per row)
__global__ __launch_bounds__(256) void reduce_softmax_kernel(
    const float* __restrict__ partial, float* __restrict__ out)
{
  int t = threadIdx.x;
  int r = blockIdx.x * 4 + (t >> 6), c = t & 63;
  size_t base = (size_t)r * 80;
  size_t stride = (size_t)NROWS * 80;
  float v = 0.f, d = 0.f;
#pragma unroll
  for (int js = 0; js < 8; ++js) {
    v += partial[js * stride + base + c];
    d += partial[js * stride + base + 64];
  }
  v /= d;
  float m = v;
  for (int o = 32; o > 0; o >>= 1) m = fmaxf(m, __shfl_xor(m, o, 64));
  float e = __expf(v - m);
  float s = e;
  for (int o = 32; o > 0; o >>= 1) s += __shfl_xor(s, o, 64);
  out[(size_t)r * 64 + c] = e / s;
}

extern "C" void kernel_launch(void* const* d_in, const int* in_sizes, int n_in,
                              void* d_out, int out_size, void* d_ws, size_t ws_size,
                              hipStream_t stream) {
  const float* feat  = (const float*)d_in[0];
  const float* Wgl0  = (const float*)d_in[6];
  const float* bgl0  = (const float*)d_in[7];
  const float* Wgnn0 = (const float*)d_in[8];
  const float* bgnn0 = (const float*)d_in[9];
  const float* Wgl1  = (const float*)d_in[10];
  const float* bgl1  = (const float*)d_in[11];
  const float* Wgnn1 = (const float*)d_in[12];
  const float* bgnn1 = (const float*)d_in[13];
  const float* temp  = (const float*)d_in[14];
  const float* theta = (const float*)d_in[15];
  float* out = (float*)d_out;

  char* ws = (char*)d_ws;
  size_t off = 0;
  auto alloc = [&](size_t bytes) {
    char* p = ws + off;
    off = (off + bytes + 255) & ~(size_t)255;
    return p;
  };
  float*    par0 = (float*)alloc(8ull * NROWS * 144 * 4);  // 37.7 MB
  float*    par1 = par0;  // aliased: par0 is consumed before fused<64> runs
  float*    x1   = (float*)alloc(8192ull * 128 * 4);
  ushort_t* glf0 = (ushort_t*)alloc((8192ull / 16) * 4 * 64 * 8 * 2);
  ushort_t* glf1 = (ushort_t*)alloc((8192ull / 16) * 2 * 64 * 8 * 2);
  ushort_t* hf0  = (ushort_t*)alloc((8192ull / 64) * 2 * 9 * 64 * 8 * 2);
  ushort_t* hf1  = (ushort_t*)alloc((8192ull / 64) * 2 * 5 * 64 * 8 * 2);
  float*    sq0  = (float*)alloc(8192ull * 4);
  float*    sq1  = (float*)alloc(8192ull * 4);
  ushort_t* Wf0  = (ushort_t*)alloc(8ull * 16 * 512 * 2);   // 128 KB
  ushort_t* Wf1  = (ushort_t*)alloc(4ull * 8 * 512 * 2);    // 32 KB

  // pack weights (one-time per launch; deterministic)
  prep_w_kernel<256, 128><<<256, 256, 0, stream>>>(Wgl0, Wgnn0, Wf0);
  prep_w_kernel<128, 64><<<64, 256, 0, stream>>>(Wgl1, Wgnn1, Wf1);

  lin_kernel<256, 128><<<512, 256, 0, stream>>>(feat, Wf0, bgl0, bgnn0, glf0, sq0, hf0);
  fused_kernel<128><<<dim3(64, 8), 256, 0, stream>>>(glf0, sq0, hf0, temp, theta, par0);
  reduce_div_kernel<128, true><<<(8192 * 128) / 256, 256, 0, stream>>>(par0, x1);

  lin_kernel<128, 64><<<512, 256, 0, stream>>>(x1, Wf1, bgl1, bgnn1, glf1, sq1, hf1);
  fused_kernel<64><<<dim3(64, 8), 256, 0, stream>>>(glf1, sq1, hf1, temp, theta, par1);
  reduce_softmax_kernel<<<2048, 256, 0, stream>>>(par1, out);
}

// Round 17
// 142.593 us; speedup vs baseline: 1.4651x; 1.0571x over previous
//
#include <hip/hip_runtime.h>
#include <hip/hip_bf16.h>

#define NROWS 8192

typedef __bf16 bf16x8 __attribute__((ext_vector_type(8)));
typedef float f32x4 __attribute__((ext_vector_type(4)));
typedef unsigned short ushort_t;
typedef unsigned int uint_t;

__device__ __forceinline__ ushort_t f2bf(float f) {
  uint_t u = __builtin_bit_cast(uint_t, f);
  u += 0x7fffu + ((u >> 16) & 1u);   // round-to-nearest-even
  return (ushort_t)(u >> 16);
}
__device__ __forceinline__ float bf2f(ushort_t h) {
  uint_t u = ((uint_t)h) << 16;
  return __builtin_bit_cast(float, u);
}
// async global->LDS DMA; LDS dest = uniform base + lane*size
__device__ __forceinline__ void load_lds16(const ushort_t* g, ushort_t* l) {
  __builtin_amdgcn_global_load_lds(
      (const __attribute__((address_space(1))) unsigned int*)g,
      (__attribute__((address_space(3))) unsigned int*)l, 16, 0, 0);
}
__device__ __forceinline__ void load_lds4(const float* g, float* l) {
  __builtin_amdgcn_global_load_lds(
      (const __attribute__((address_space(1))) unsigned int*)g,
      (__attribute__((address_space(3))) unsigned int*)l, 4, 0, 0);
}

// ---------------------------------------------------------------------------
// prep_w: pack Wcat=[W1|W2] (fp32) into fragment-major bf16 Wf.
// ---------------------------------------------------------------------------
template<int DIN, int F>
__global__ __launch_bounds__(256) void prep_w_kernel(
    const float* __restrict__ W1, const float* __restrict__ W2,
    ushort_t* __restrict__ Wf)
{
  constexpr int NCT = (2 * F) / 16;
  int idx = blockIdx.x * 256 + threadIdx.x;   // grid sized exactly
  int e = idx & 7, lane = (idx >> 3) & 63;
  int ct = (idx >> 9) % NCT, kk = (idx >> 9) / NCT;
  int g = lane >> 4, q = lane & 15;
  int k = 32 * kk + 8 * g + e, c = 16 * ct + q;
  float v = (c < F) ? W1[(size_t)k * F + c] : W2[(size_t)k * F + (c - F)];
  Wf[idx] = f2bf(v);
}

// ---------------------------------------------------------------------------
// lin (R17): MFMA GEMM for [gl|h] = x @ [W1|W2] + b. RED=true (layer 1):
// x is produced inline by reducing the 8 partial slabs (fuses reduce_div:
// x[r][c] = max(sum_js par[js][r][c], 0) / sum_js par[js][r][128]).
// ---------------------------------------------------------------------------
template<int DIN, int F, bool RED>
__global__ __launch_bounds__(256) void lin_kernel(
    const float* __restrict__ x, const ushort_t* __restrict__ Wf,
    const float* __restrict__ b1, const float* __restrict__ b2,
    ushort_t* __restrict__ glf, float* __restrict__ sq, ushort_t* __restrict__ hf)
{
  constexpr int Fp   = F + 16;
  constexpr int NT   = Fp / 16;
  constexpr int KK   = F / 32;       // packer fragments (gl)
  constexpr int KKD  = DIN / 32;     // GEMM K-fragments
  constexpr int NCT  = (2 * F) / 16; // output col-tiles (gl|h)
  constexpr int NCTW = NCT / 4;      // col-tiles per wave
  __shared__ float    xs[16][DIN];
  __shared__ float    hs[16][F];
  __shared__ ushort_t gls[16][F];
  __shared__ float    sqs[16];
  __shared__ float    degs[16];
  const int t  = threadIdx.x;
  const int m  = blockIdx.x;
  const int r0 = m * 16;
  const int w = t >> 6, lane = t & 63, g = lane >> 4, q = lane & 15;

  if (RED) {
    // fused reduce_div: deg first, then reduced+relu'd elements into xs
    constexpr size_t STR = (size_t)NROWS * 144;
    if (t < 16) {
      float d = 0.f;
#pragma unroll
      for (int js = 0; js < 8; ++js)
        d += x[js * STR + (size_t)(r0 + t) * 144 + 128];
      degs[t] = d;
    }
    __syncthreads();
    for (int i = t; i < 16 * DIN; i += 256) {
      int r = i / DIN, c = i % DIN;
      float s = 0.f;
#pragma unroll
      for (int js = 0; js < 8; ++js)
        s += x[js * STR + (size_t)(r0 + r) * 144 + c];
      xs[r][c] = fmaxf(s, 0.f) / degs[r];
    }
  } else {
    for (int i = t; i < 16 * DIN; i += 256)
      xs[i / DIN][i % DIN] = x[(size_t)(r0 + i / DIN) * DIN + (i % DIN)];
  }
  if (t < 16) sqs[t] = 0.f;
  __syncthreads();

  // A-frags: lane(g,q) elem e = bf16(xs[q][32kk+8g+e])
  bf16x8 aF[KKD];
#pragma unroll
  for (int kk = 0; kk < KKD; ++kk) {
    const float* src = &xs[q][32 * kk + 8 * g];
    __align__(16) ushort_t tmp[8];
#pragma unroll
    for (int e = 0; e < 8; ++e) tmp[e] = f2bf(src[e]);
    aF[kk] = *(const bf16x8*)tmp;
  }
  // acc init = bias broadcast
  f32x4 acc[NCTW];
#pragma unroll
  for (int tl = 0; tl < NCTW; ++tl) {
    int c = 16 * (NCTW * w + tl) + q;
    float bv = (c < F) ? b1[c] : b2[c - F];
    acc[tl] = (f32x4){bv, bv, bv, bv};
  }
#pragma unroll
  for (int kk = 0; kk < KKD; ++kk)
#pragma unroll
    for (int tl = 0; tl < NCTW; ++tl) {
      bf16x8 bW = *(const bf16x8*)(Wf +
          ((size_t)(kk * NCT) + (NCTW * w + tl)) * 512 + lane * 8);
      acc[tl] = __builtin_amdgcn_mfma_f32_16x16x32_bf16(aF[kk], bW, acc[tl], 0, 0, 0);
    }
  // epilogue: D[row=4g+r][col=16ct+q] -> gls (relu+bf16, +sq) or hs
#pragma unroll
  for (int tl = 0; tl < NCTW; ++tl)
#pragma unroll
    for (int r = 0; r < 4; ++r) {
      int row = 4 * g + r, c = 16 * (NCTW * w + tl) + q;
      float v = acc[tl][r];
      if (c < F) {
        float gv = fmaxf(v, 0.f);
        ushort_t gb = f2bf(gv);
        gls[row][c] = gb;
        float gf = bf2f(gb);
        atomicAdd(&sqs[row], gf * gf);
      } else {
        hs[row][c - F] = v;
      }
    }
  __syncthreads();
  if (t < 16) sq[r0 + t] = sqs[t];

  // ---- glf writer (unchanged)
  {
    constexpr int CH = KK * 64;
    if (t < CH) {
      int kk = t >> 6, li = t & 63;
      int row = li & 15, c0 = 32 * kk + 8 * (li >> 4);
      uint4 v = *(const uint4*)&gls[row][c0];
      *(uint4*)(glf + ((size_t)(m * KK + kk) * 64 + li) * 8) = v;
    }
  }
  // ---- hf writer (unchanged)
  {
    const int jc  = m >> 2;
    const int P   = (m >> 1) & 1;
    const int glo = (m & 1) * 2;
    for (int idx = t; idx < NT * 32; idx += 256) {
      int t2 = idx >> 5, li = idx & 31;
      int gg = li >> 4, qq = li & 15;
      int feat = 16 * t2 + qq;
      ushort_t tmp[8];
#pragma unroll
      for (int e = 0; e < 8; ++e) {
        if (feat < F)        tmp[e] = f2bf(hs[8 * gg + e][feat]);
        else if (feat == F)  tmp[e] = (ushort_t)0x3F80;  // bf16(1.0)
        else                 tmp[e] = 0;
      }
      int ln = (glo + gg) * 16 + qq;
      uint4* dst = (uint4*)(hf + ((size_t)((jc * 2 + P) * NT + t2) * 64 + ln) * 8);
      *dst = *(const uint4*)tmp;
    }
  }
}

// ---------------------------------------------------------------------------
// fused (R17 = R14 + XCD swizzle): block linear id n -> (y=n&7, x=n>>3).
// gridDim.y == 8 == NXCD, so XCD k (n%8==k under round-robin dispatch) owns
// j-chunk k exclusively -> per-XCD working set ~2.5MB fits 4MB L2 (was 3.9x
// HBM over-fetch: 16.6MB FETCH vs 4.3MB unique).
// ---------------------------------------------------------------------------
template<int F>
__global__ __launch_bounds__(256) void fused_kernel(
    const ushort_t* __restrict__ glf, const float* __restrict__ sq,
    const ushort_t* __restrict__ hf,
    const float* __restrict__ temp_p, const float* __restrict__ theta_p,
    float* __restrict__ partial)
{
  constexpr int Fp   = F + 16;
  constexpr int NT   = Fp / 16;
  constexpr int KK   = F / 32;
  constexpr int JS   = 8;
  constexpr int JCH  = NROWS / JS;
  constexpr int NIT  = JCH / 32;
  constexpr int NCHB = 2 * KK;
  constexpr int NHF  = NT - 1;
  constexpr int NCH  = NCHB + NHF;
  constexpr float EPS = 1.1920929e-07f;
  constexpr float LOG2E = 1.4426950408889634f;
  __shared__ __align__(16) ushort_t stage[NCH * 512 + 128];
  __shared__ __align__(16) ushort_t adjlds[128 * 32];

  const int w = threadIdx.x >> 6, lane = threadIdx.x & 63;
  const int g = lane >> 4, q = lane & 15;
  // XCD-aware remap: n%8 -> j-chunk (XCD-affine), n/8 -> i-tile
  const int n  = blockIdx.x + (int)gridDim.x * blockIdx.y;
  const int bx = n >> 3, by = n & 7;
  const int irow  = bx * 128 + 32 * w;
  const int jbase = by * JCH;
  const float c1 = 1.0f + *temp_p;
  const float c0 = 5.0f + *theta_p;
  const float k1 = c1 * LOG2E;
  const float k0 = -c0 * LOG2E;

  bf16x8 aF[2][KK];
#pragma unroll
  for (int s = 0; s < 2; ++s)
#pragma unroll
    for (int kk = 0; kk < KK; ++kk)
      aF[s][kk] = *(const bf16x8*)(glf +
          ((size_t)(((irow >> 4) + s) * KK + kk) * 64 + lane) * 8);
  float sqi[2][4];
#pragma unroll
  for (int s = 0; s < 2; ++s)
#pragma unroll
    for (int r = 0; r < 4; ++r) sqi[s][r] = sq[irow + 16 * s + 4 * g + r] + EPS;

  bf16x8 onesF;
  {
    __align__(16) ushort_t tmp[8];
    ushort_t v = (q == 0) ? (ushort_t)0x3F80 : (ushort_t)0;
#pragma unroll
    for (int e = 0; e < 8; ++e) tmp[e] = v;
    onesF = *(const bf16x8*)tmp;
  }

  ushort_t* wp[8];
#pragma unroll
  for (int tt = 0; tt < 2; ++tt)
#pragma unroll
    for (int r = 0; r < 4; ++r) {
      int row = 32 * w + 4 * g + r;
      int colb = 32 * tt + 2 * q;
      wp[tt * 4 + r] = (ushort_t*)((char*)adjlds
                        + row * 64 + (colb ^ (((row >> 2) & 3) << 4)));
    }
  const ushort_t* rp;
  {
    int row = 32 * w + q;
    rp = (const ushort_t*)((char*)adjlds
          + row * 64 + ((16 * g) ^ (((row >> 2) & 3) << 4)));
  }
  const float* sql = (const float*)(stage + NCH * 512) + q;

  f32x4 acc[2][NT];
#pragma unroll
  for (int s = 0; s < 2; ++s)
#pragma unroll
    for (int i = 0; i < NT; ++i) acc[s][i] = (f32x4){0.f, 0.f, 0.f, 0.f};

#pragma unroll 1
  for (int k = 0; k < NIT; ++k) {
    const int j0 = jbase + k * 32;
    __syncthreads();
    {
      const ushort_t* glB = glf + (size_t)(j0 >> 4) * KK * 512;
      const ushort_t* glH = hf  + (size_t)(j0 >> 5) * NT * 512;
#pragma unroll
      for (int ch = w; ch < NCH; ch += 4) {
        const ushort_t* src = (ch < NCHB) ? (glB + (size_t)ch * 512)
                                          : (glH + (size_t)(ch - NCHB) * 512);
        load_lds16(src + lane * 8, stage + ch * 512);
      }
      if (w == 3 && lane < 32)
        load_lds4(sq + j0 + lane, (float*)(stage + NCH * 512) + lane);
    }
    __syncthreads();

    f32x4 sA[2][2];
    float sqj[2];
#pragma unroll
    for (int tt = 0; tt < 2; ++tt) {
      sqj[tt] = sql[16 * tt];
      f32x4 c0a = (f32x4){0.f, 0.f, 0.f, 0.f};
      f32x4 c1a = (f32x4){0.f, 0.f, 0.f, 0.f};
#pragma unroll
      for (int kk = 0; kk < KK; ++kk) {
        bf16x8 b = *(const bf16x8*)(stage + (tt * KK + kk) * 512 + lane * 8);
        c0a = __builtin_amdgcn_mfma_f32_16x16x32_bf16(aF[0][kk], b, c0a, 0, 0, 0);
        c1a = __builtin_amdgcn_mfma_f32_16x16x32_bf16(aF[1][kk], b, c1a, 0, 0, 0);
      }
      sA[0][tt] = c0a;
      sA[1][tt] = c1a;
    }
#pragma unroll
    for (int s = 0; s < 2; ++s)
#pragma unroll
      for (int tt = 0; tt < 2; ++tt)
#pragma unroll
        for (int r = 0; r < 4; ++r) {
          float t1 = sqi[s][r] + sqj[tt];
          float d  = fmaxf(fmaf(-2.f, sA[s][tt][r], t1), EPS);
          float e  = __builtin_amdgcn_exp2f(
                       fmaf(k1, __builtin_amdgcn_sqrtf(d), k0));
          float adjv = __builtin_amdgcn_rcpf(1.f + e);
          uint_t u = __builtin_bit_cast(uint_t, adjv) + 0x8000u;
          *(wp[tt * 4 + r] + s * 512) = (ushort_t)(u >> 16);
        }
    asm volatile("s_waitcnt lgkmcnt(0)" ::: "memory");
    {
      bf16x8 aP0 = *(const bf16x8*)(rp);
      bf16x8 aP1 = *(const bf16x8*)(rp + 512);
#pragma unroll
      for (int t2 = 0; t2 < NT; ++t2) {
        bf16x8 hF = (t2 == NT - 1)
            ? onesF
            : *(const bf16x8*)(stage + (NCHB + t2) * 512 + lane * 8);
        acc[0][t2] = __builtin_amdgcn_mfma_f32_16x16x32_bf16(aP0, hF, acc[0][t2], 0, 0, 0);
        acc[1][t2] = __builtin_amdgcn_mfma_f32_16x16x32_bf16(aP1, hF, acc[1][t2], 0, 0, 0);
      }
    }
  }

  float* op = partial + ((size_t)by * NROWS + irow) * Fp;
#pragma unroll
  for (int s = 0; s < 2; ++s)
#pragma unroll
    for (int t2 = 0; t2 < NT; ++t2)
#pragma unroll
      for (int r = 0; r < 4; ++r)
        op[(size_t)(16 * s + 4 * g + r) * Fp + 16 * t2 + q] = acc[s][t2][r];
}

// out = softmax(sum_js(partial)/deg) rowwise; 4 rows/block (wave per row)
__global__ __launch_bounds__(256) void reduce_softmax_kernel(
    const float* __restrict__ partial, float* __restrict__ out)
{
  int t = threadIdx.x;
  int r = blockIdx.x * 4 + (t >> 6), c = t & 63;
  size_t base = (size_t)r * 80;
  size_t stride = (size_t)NROWS * 80;
  float v = 0.f, d = 0.f;
#pragma unroll
  for (int js = 0; js < 8; ++js) {
    v += partial[js * stride + base + c];
    d += partial[js * stride + base + 64];
  }
  v /= d;
  float m = v;
  for (int o = 32; o > 0; o >>= 1) m = fmaxf(m, __shfl_xor(m, o, 64));
  float e = __expf(v - m);
  float s = e;
  for (int o = 32; o > 0; o >>= 1) s += __shfl_xor(s, o, 64);
  out[(size_t)r * 64 + c] = e / s;
}

extern "C" void kernel_launch(void* const* d_in, const int* in_sizes, int n_in,
                              void* d_out, int out_size, void* d_ws, size_t ws_size,
                              hipStream_t stream) {
  const float* feat  = (const float*)d_in[0];
  const float* Wgl0  = (const float*)d_in[6];
  const float* bgl0  = (const float*)d_in[7];
  const float* Wgnn0 = (const float*)d_in[8];
  const float* bgnn0 = (const float*)d_in[9];
  const float* Wgl1  = (const float*)d_in[10];
  const float* bgl1  = (const float*)d_in[11];
  const float* Wgnn1 = (const float*)d_in[12];
  const float* bgnn1 = (const float*)d_in[13];
  const float* temp  = (const float*)d_in[14];
  const float* theta = (const float*)d_in[15];
  float* out = (float*)d_out;

  char* ws = (char*)d_ws;
  size_t off = 0;
  auto alloc = [&](size_t bytes) {
    char* p = ws + off;
    off = (off + bytes + 255) & ~(size_t)255;
    return p;
  };
  float*    par0 = (float*)alloc(8ull * NROWS * 144 * 4);  // 37.7 MB
  float*    par1 = par0;  // aliased: par0 fully consumed by lin1 first
  ushort_t* glf0 = (ushort_t*)alloc((8192ull / 16) * 4 * 64 * 8 * 2);
  ushort_t* glf1 = (ushort_t*)alloc((8192ull / 16) * 2 * 64 * 8 * 2);
  ushort_t* hf0  = (ushort_t*)alloc((8192ull / 64) * 2 * 9 * 64 * 8 * 2);
  ushort_t* hf1  = (ushort_t*)alloc((8192ull / 64) * 2 * 5 * 64 * 8 * 2);
  float*    sq0  = (float*)alloc(8192ull * 4);
  float*    sq1  = (float*)alloc(8192ull * 4);
  ushort_t* Wf0  = (ushort_t*)alloc(8ull * 16 * 512 * 2);   // 128 KB
  ushort_t* Wf1  = (ushort_t*)alloc(4ull * 8 * 512 * 2);    // 32 KB

  prep_w_kernel<256, 128><<<256, 256, 0, stream>>>(Wgl0, Wgnn0, Wf0);
  prep_w_kernel<128, 64><<<64, 256, 0, stream>>>(Wgl1, Wgnn1, Wf1);

  lin_kernel<256, 128, false><<<512, 256, 0, stream>>>(feat, Wf0, bgl0, bgnn0, glf0, sq0, hf0);
  fused_kernel<128><<<dim3(64, 8), 256, 0, stream>>>(glf0, sq0, hf0, temp, theta, par0);

  // lin1 fuses reduce_div: reads the 8 partial slabs directly
  lin_kernel<128, 64, true><<<512, 256, 0, stream>>>(par0, Wf1, bgl1, bgnn1, glf1, sq1, hf1);
  fused_kernel<64><<<dim3(64, 8), 256, 0, stream>>>(glf1, sq1, hf1, temp, theta, par1);
  reduce_softmax_kernel<<<2048, 256, 0, stream>>>(par1, out);
}